// Round 7
// baseline (1485.524 us; speedup 1.0000x reference)
//
#include <hip/hip_runtime.h>
#include <cstdint>
#include <cstddef>

#define T_STEPS 512
#define F       128
#define ROWS    16
#define NBT     32                 // batch tiles = blocks
#define BLOCK   1024               // 16 waves: 0-7 scan, 8-15 producer
#define FP      (F + 8)            // fp16 LDS row stride for h
#define DEPTH   3                  // xp ring slots
#define L2E     1.4426950408889634f

typedef __attribute__((ext_vector_type(8))) _Float16 half8;
typedef __attribute__((ext_vector_type(4))) _Float16 half4;
typedef __attribute__((ext_vector_type(2))) __fp16   pkh2;
typedef __attribute__((ext_vector_type(4))) float    f32x4;

__device__ __forceinline__ float frcp_(float x)  { return __builtin_amdgcn_rcpf(x); }
__device__ __forceinline__ float fexp2_(float x) { return __builtin_amdgcn_exp2f(x); }

// LDS-only barrier: ds ops drained (producer->scan handoff), globals may fly
__device__ __forceinline__ void lds_barrier() {
    asm volatile("s_waitcnt lgkmcnt(0)\n\ts_barrier" ::: "memory");
}

// B-fragments for 4 matrices, pre-scaled by L2E (2*L2E for tanh gate g=2):
// fr[g][kc] holds B[k=kc*32+quad*8+j][ncol]
__device__ __forceinline__ void load_bfrags(const float* const* mats, int quad, int ncol,
                                            half8 fr[4][4]) {
    const float scl[4] = {L2E, L2E, 2.f * L2E, L2E};
    #pragma unroll
    for (int g = 0; g < 4; ++g) {
        #pragma unroll
        for (int kc = 0; kc < 4; ++kc) {
            half8 v;
            #pragma unroll
            for (int j = 0; j < 4; ++j) {
                const int k = kc * 32 + quad * 8 + 2 * j;
                pkh2 p = __builtin_amdgcn_cvt_pkrtz(mats[g][k * F + ncol] * scl[g],
                                                    mats[g][(k + 1) * F + ncol] * scl[g]);
                v[2 * j] = (_Float16)p[0]; v[2 * j + 1] = (_Float16)p[1];
            }
            fr[g][kc] = v;
        }
    }
}

// ============================================================================
// One kernel, 32 blocks of 16 waves. Waves 0-7: sequential LSTM scan for this
// batch tile. Waves 8-15: x-projection producer, one t-step per scan step into
// an LDS ring (slot tp%3). Schedule (step t): scan USES regs of t, ds_reads
// slot (t+1)%3, producer ds_writes slot (t+2)%3 — pairwise disjoint mod 3;
// handoff ordered by the shared per-step lds_barrier. No global xp, no flags.
// ============================================================================
__global__ __launch_bounds__(BLOCK, 4)
void lstm_fused2(const float* __restrict__ x,
                 const float* __restrict__ wh0, const float* __restrict__ wx0, const float* __restrict__ b0,
                 const float* __restrict__ wh1, const float* __restrict__ wx1, const float* __restrict__ b1,
                 const float* __restrict__ wh2, const float* __restrict__ wx2, const float* __restrict__ b2,
                 const float* __restrict__ wh3, const float* __restrict__ wx3, const float* __restrict__ b3,
                 float* __restrict__ out)
{
    __shared__ _Float16 h_lds[2][ROWS * FP];          // 8.7 KB
    __shared__ half4    ring[DEPTH][4][F][4];         // [slot][gate][col][quad] rows 4q..4q+3 — 48 KB

    const int tid  = threadIdx.x;
    const int w    = tid >> 6;
    const int lane = tid & 63;
    const int quad = lane >> 4;
    const int l16  = lane & 15;
    const int bt   = blockIdx.x;
    const int row0 = bt * ROWS;

    if (w < 8) {
        // ========================= SCAN (waves 0-7) =========================
        const int ncol = w * 16 + l16;
        const float* mats[4] = {wh0, wh1, wh2, wh3};
        half8 whfr[4][4];
        load_bfrags(mats, quad, ncol, whfr);

        for (int i = tid; i < ROWS * FP; i += 512) h_lds[0][i] = (_Float16)0.f;

        lds_barrier();                         // B1: producer prologue (slots 0,1) visible

        half4 xv[4];                           // preacts for step t (fp16, C-frag layout)
        #pragma unroll
        for (int g = 0; g < 4; ++g) xv[g] = ring[0][g][ncol][quad];

        float c_st[4] = {0.f, 0.f, 0.f, 0.f};
        float h_f[4]  = {0.f, 0.f, 0.f, 0.f};
        int sl_next = 1;                       // slot of t+1

        for (int t = 0; t < T_STEPS; ++t) {
            const int cur = t & 1;

            half8 ah[4];
            #pragma unroll
            for (int kc = 0; kc < 4; ++kc)
                ah[kc] = *(const half8*)&h_lds[cur][l16 * FP + kc * 32 + quad * 8];

            f32x4 acc[4];
            #pragma unroll
            for (int g = 0; g < 4; ++g) {
                #pragma unroll
                for (int r = 0; r < 4; ++r) acc[g][r] = (float)xv[g][r];
            }

            // fetch next step's preacts (slot (t+1)%3, written during step t-1)
            if (t + 1 < T_STEPS) {
                #pragma unroll
                for (int g = 0; g < 4; ++g) xv[g] = ring[sl_next][g][ncol][quad];
            }
            sl_next = (sl_next == DEPTH - 1) ? 0 : sl_next + 1;

            #pragma unroll
            for (int kc = 0; kc < 4; ++kc) {
                #pragma unroll
                for (int g = 0; g < 4; ++g)
                    acc[g] = __builtin_amdgcn_mfma_f32_16x16x32_f16(ah[kc], whfr[g][kc], acc[g], 0, 0, 0);
            }

            // gates: 5 exp2 + 2 rcp per element (shared rcp across 4 denoms)
            #pragma unroll
            for (int r = 0; r < 4; ++r) {
                const float e1 = fexp2_(-acc[0][r]);
                const float e2 = fexp2_(-acc[1][r]);
                const float e3 = fexp2_(-acc[2][r]);
                const float e4 = fexp2_(-acc[3][r]);
                const float d1 = 1.f + e1, d2 = 1.f + e2, d3 = 1.f + e3, d4 = 1.f + e4;
                const float pa = d1 * d2, pb = d3 * d4;
                const float r0 = frcp_(pa * pb);
                const float ra = r0 * pb, rb = r0 * pa;
                const float ig = ra * d2;                    // 1/d1
                const float fg = ra * d1;                    // 1/d2
                const float gt = 2.f * (rb * d4) - 1.f;      // tanh = 2/d3 - 1
                const float ot = rb * d3;                    // 1/d4
                const float cn = fg * c_st[r] + ig * gt;
                c_st[r] = cn;
                const float th = 2.f * frcp_(1.f + fexp2_(-2.f * L2E * cn)) - 1.f;
                const float hh = ot * th;
                h_f[r] = hh;
                h_lds[cur ^ 1][(quad * 4 + r) * FP + ncol] = (_Float16)hh;
            }
            lds_barrier();
        }

        #pragma unroll
        for (int r = 0; r < 4; ++r)
            out[(size_t)(row0 + quad * 4 + r) * F + ncol] = h_f[r];
    } else {
        // ======================= PRODUCER (waves 8-15) ======================
        const int ncol = (w - 8) * 16 + l16;
        const float* mats[4] = {wx0, wx1, wx2, wx3};
        const float* bpp[4]  = {b0, b1, b2, b3};
        const float scl[4]   = {L2E, L2E, 2.f * L2E, L2E};
        half8 bfr[4][4];
        load_bfrags(mats, quad, ncol, bfr);
        float bias_v[4];
        #pragma unroll
        for (int g = 0; g < 4; ++g) bias_v[g] = bpp[g][ncol] * scl[g];

        const float* xrow = &x[(size_t)(row0 + l16) * (T_STEPS * F) + quad * 8];

        // lambda-ish helper inlined: produce t-step tp into ring slot sl
        #define PRODUCE(tp, sl)                                                          \
        {                                                                                \
            half8 afr[4];                                                                \
            _Pragma("unroll")                                                            \
            for (int kc = 0; kc < 4; ++kc) {                                             \
                const float* px = xrow + (size_t)(tp) * F + kc * 32;                     \
                const f32x4 u0 = *(const f32x4*)px;                                      \
                const f32x4 u1 = *(const f32x4*)(px + 4);                                \
                half8 v;                                                                 \
                _Pragma("unroll")                                                        \
                for (int j = 0; j < 2; ++j) {                                            \
                    pkh2 p0 = __builtin_amdgcn_cvt_pkrtz(u0[2 * j], u0[2 * j + 1]);      \
                    pkh2 p1 = __builtin_amdgcn_cvt_pkrtz(u1[2 * j], u1[2 * j + 1]);      \
                    v[2 * j] = (_Float16)p0[0]; v[2 * j + 1] = (_Float16)p0[1];          \
                    v[4 + 2 * j] = (_Float16)p1[0]; v[5 + 2 * j] = (_Float16)p1[1];      \
                }                                                                        \
                afr[kc] = v;                                                             \
            }                                                                            \
            f32x4 acc[4];                                                                \
            _Pragma("unroll")                                                            \
            for (int g = 0; g < 4; ++g)                                                  \
                acc[g] = (f32x4){bias_v[g], bias_v[g], bias_v[g], bias_v[g]};            \
            _Pragma("unroll")                                                            \
            for (int kc = 0; kc < 4; ++kc) {                                             \
                _Pragma("unroll")                                                        \
                for (int g = 0; g < 4; ++g)                                              \
                    acc[g] = __builtin_amdgcn_mfma_f32_16x16x32_f16(afr[kc], bfr[g][kc], \
                                                                    acc[g], 0, 0, 0);   \
            }                                                                            \
            _Pragma("unroll")                                                            \
            for (int g = 0; g < 4; ++g) {                                                \
                pkh2 p0 = __builtin_amdgcn_cvt_pkrtz(acc[g][0], acc[g][1]);              \
                pkh2 p1 = __builtin_amdgcn_cvt_pkrtz(acc[g][2], acc[g][3]);              \
                half4 hv;                                                                \
                hv[0] = (_Float16)p0[0]; hv[1] = (_Float16)p0[1];                        \
                hv[2] = (_Float16)p1[0]; hv[3] = (_Float16)p1[1];                        \
                ring[sl][g][ncol][quad] = hv;                                            \
            }                                                                            \
        }

        PRODUCE(0, 0)
        PRODUCE(1, 1)
        lds_barrier();                         // B1

        int sl = 2;                            // slot of t+2 at t=0
        for (int t = 0; t < T_STEPS; ++t) {
            if (t + 2 < T_STEPS) PRODUCE(t + 2, sl)
            sl = (sl == DEPTH - 1) ? 0 : sl + 1;
            lds_barrier();
        }
        #undef PRODUCE
    }
}

extern "C" void kernel_launch(void* const* d_in, const int* in_sizes, int n_in,
                              void* d_out, int out_size, void* d_ws, size_t ws_size,
                              hipStream_t stream) {
    const float* x   = (const float*)d_in[0];
    const float* whi = (const float*)d_in[1];
    const float* wxi = (const float*)d_in[2];
    const float* bi  = (const float*)d_in[3];
    const float* whf = (const float*)d_in[4];
    const float* wxf = (const float*)d_in[5];
    const float* bf  = (const float*)d_in[6];
    const float* whg = (const float*)d_in[7];
    const float* wxg = (const float*)d_in[8];
    const float* bg  = (const float*)d_in[9];
    const float* who = (const float*)d_in[10];
    const float* wxo = (const float*)d_in[11];
    const float* bo  = (const float*)d_in[12];
    float* out = (float*)d_out;

    hipLaunchKernelGGL(lstm_fused2, dim3(NBT), dim3(BLOCK), 0, stream,
                       x, whi, wxi, bi, whf, wxf, bf, whg, wxg, bg, who, wxo, bo, out);
}